// Round 7
// baseline (300.190 us; speedup 1.0000x reference)
//
#include <hip/hip_runtime.h>

#define B_ 8
#define C_ 19
#define H_ 512
#define W_ 512
#define HW_ (H_*W_)

#define HALO   20
#define INTR   8             // interior rows per strip
#define NSTRIP 64            // 64*8 = 512

typedef unsigned long long u64;

// ---------- pass A: bit-pack target into per-class masks ---------------------
__global__ __launch_bounds__(256) void mask_kernel(const int* __restrict__ target,
                                                   u64* __restrict__ masks) {
    __shared__ u64 mlds[64][21];
    const int blk  = blockIdx.x;          // 512 blocks, 64 per image
    const int b    = blk >> 6;
    const int base = (blk & 63) * 64;     // first word within image
    const int tid  = threadIdx.x;
    const int lane = tid & 63, wv = tid >> 6;
    const int* tgt = target + b * HW_;
    for (int t = 0; t < 16; ++t) {
        const int cl = wv * 16 + t;       // chunk-local word 0..63
        const int x  = tgt[(base + cl) * 64 + lane];
        u64 keep = 0;
        #pragma unroll
        for (int c = 0; c < C_; ++c) {
            u64 m = __ballot(x == c);
            if (lane == c) keep = m;
        }
        if (lane < C_) mlds[cl][lane] = keep;
    }
    __syncthreads();
    for (int idx = tid; idx < C_ * 64; idx += 256) {
        const int c = idx >> 6, wl = idx & 63;
        masks[((size_t)b * C_ + c) * 4096 + base + wl] = mlds[wl][c];
    }
}

// ---------- pass B: dilation, ONE WAVE PER (b,c,strip) WINDOW ----------------
// 9728 independent waves; no LDS, no barriers. Wave holds 48x512 window in
// registers: lane=(rowgroup g=lane>>3, word-col w=lane&7), 6 rows/lane.
// Row exchange: __shfl +-8; word carry: __shfl +-1. First-covered-step ->
// 5 bit-planes; iso folded into plane0 at step 1; uncovered at end -> 20.
// Interior 8 rows stored to global sdf as transposed bytes (16B stores).
__global__ __launch_bounds__(256) void dilate_kernel(const u64* __restrict__ masks,
                                                     unsigned char* __restrict__ sdf) {
    const int wid   = blockIdx.x * 4 + (threadIdx.x >> 6);  // 0..9727
    const int strip = wid & 63;           // fastest -> block-local mask reuse
    const int bc    = wid >> 6;           // 0..151
    const int lane  = threadIdx.x & 63;
    const int w     = lane & 7, g = lane >> 3;
    const int gytop = strip * INTR - HALO;
    const u64* mk   = masks + (size_t)bc * 4096;

    u64 cov[6], h[6], pl[6][5];
    #pragma unroll
    for (int i = 0; i < 6; ++i) {
        const int gy = gytop + g * 6 + i;
        cov[i] = (gy >= 0 && gy < H_) ? mk[gy * 8 + w] : 0;
        #pragma unroll
        for (int j = 0; j < 5; ++j) pl[i][j] = 0;
    }

    // ---- step 1: exclude-center neighbor set; iso -> plane0; then union
    bool active;
    {
        u64 nc[6];
        unsigned mp = 0, lp = 0;
        #pragma unroll
        for (int i = 0; i < 6; ++i) {
            mp |= (unsigned)(cov[i] >> 63) << i;
            lp |= ((unsigned)cov[i] & 1) << i;
        }
        unsigned fl = __shfl_up(mp, 1);   if (w == 0) fl = 0;
        unsigned fr = __shfl_down(lp, 1); if (w == 7) fr = 0;
        #pragma unroll
        for (int i = 0; i < 6; ++i) {
            nc[i] = (cov[i] << 1) | (cov[i] >> 1) | (u64)((fl >> i) & 1) | ((u64)((fr >> i) & 1) << 63);
            h[i]  = nc[i] | cov[i];
        }
        u64 hup = __shfl_up(h[5], 8);   if (g == 0) hup = 0;
        u64 hdn = __shfl_down(h[0], 8); if (g == 7) hdn = 0;
        u64 diffw = 0;
        #pragma unroll
        for (int i = 0; i < 6; ++i) {
            const u64 up  = (i > 0) ? h[i - 1] : hup;
            const u64 dn  = (i < 5) ? h[i + 1] : hdn;
            const u64 nbr = nc[i] | up | dn;
            const u64 nb  = nbr & ~cov[i];
            pl[i][0] = nb | (cov[i] & ~nbr);   // first-reached@1 | isolated fg
            diffw |= nb;
            cov[i] |= nbr;
        }
        // rebuild h from new cov
        mp = 0; lp = 0;
        #pragma unroll
        for (int i = 0; i < 6; ++i) {
            mp |= (unsigned)(cov[i] >> 63) << i;
            lp |= ((unsigned)cov[i] & 1) << i;
        }
        fl = __shfl_up(mp, 1);   if (w == 0) fl = 0;
        fr = __shfl_down(lp, 1); if (w == 7) fr = 0;
        #pragma unroll
        for (int i = 0; i < 6; ++i)
            h[i] = cov[i] | (cov[i] << 1) | (cov[i] >> 1) | (u64)((fl >> i) & 1) | ((u64)((fr >> i) & 1) << 63);
        active = __any(diffw != 0);
    }

    // ---- steps 2..19: d[r] = h[r-1]|h[r]|h[r+1]; wave-wide early exit
    if (active) {
        #pragma unroll
        for (int s = 2; s <= 19; ++s) {
            u64 hup = __shfl_up(h[5], 8);   if (g == 0) hup = 0;
            u64 hdn = __shfl_down(h[0], 8); if (g == 7) hdn = 0;
            u64 diffw = 0;
            #pragma unroll
            for (int i = 0; i < 6; ++i) {
                const u64 up = (i > 0) ? h[i - 1] : hup;
                const u64 dn = (i < 5) ? h[i + 1] : hdn;
                const u64 d  = up | h[i] | dn;
                const u64 nb = d ^ cov[i];   // newly covered (monotone)
                diffw |= nb;
                if (s & 1)  pl[i][0] |= nb;
                if (s & 2)  pl[i][1] |= nb;
                if (s & 4)  pl[i][2] |= nb;
                if (s & 8)  pl[i][3] |= nb;
                if (s & 16) pl[i][4] |= nb;
                cov[i] = d;
            }
            if (!__any(diffw != 0)) break;
            if (s < 19) {
                unsigned mp = 0, lp = 0;
                #pragma unroll
                for (int i = 0; i < 6; ++i) {
                    mp |= (unsigned)(cov[i] >> 63) << i;
                    lp |= ((unsigned)cov[i] & 1) << i;
                }
                unsigned fl = __shfl_up(mp, 1);   if (w == 0) fl = 0;
                unsigned fr = __shfl_down(lp, 1); if (w == 7) fr = 0;
                #pragma unroll
                for (int i = 0; i < 6; ++i)
                    h[i] = cov[i] | (cov[i] << 1) | (cov[i] >> 1) | (u64)((fl >> i) & 1) | ((u64)((fr >> i) & 1) << 63);
            }
        }
    }

    // ---- epilogue: interior rows -> transposed bytes -> global (16B stores)
    #pragma unroll
    for (int i = 0; i < 6; ++i) {
        const int lr = g * 6 + i;
        if (lr < HALO || lr >= HALO + INTR) continue;
        const int gy = gytop + lr;           // always in [0, 512)
        const u64 m = ~cov[i];               // never covered -> 20 = 0b10100
        pl[i][2] |= m;
        pl[i][4] |= m;
        union { u64 q[8]; uint4 v[4]; } o;
        #pragma unroll
        for (int g2 = 0; g2 < 8; ++g2) {
            u64 x = 0;
            #pragma unroll
            for (int j = 0; j < 5; ++j)
                x |= ((pl[i][j] >> (8 * g2)) & 0xFFULL) << (8 * j);
            u64 t;
            t = (x ^ (x >> 7))  & 0x00AA00AA00AA00AAULL; x ^= t ^ (t << 7);
            t = (x ^ (x >> 14)) & 0x0000CCCC0000CCCCULL; x ^= t ^ (t << 14);
            t = (x ^ (x >> 28)) & 0x00000000F0F0F0F0ULL; x ^= t ^ (t << 28);
            o.q[g2] = x;                     // byte p = value of pixel g2*8+p
        }
        uint4* dst = (uint4*)(sdf + (size_t)bc * HW_ + gy * W_ + w * 64);
        #pragma unroll
        for (int k = 0; k < 4; ++k) dst[k] = o.v[k];
    }
}

// ---------- pass C: loss — stream pred ONCE, num+den in one pass -------------
__global__ __launch_bounds__(256) void loss_kernel(const float* __restrict__ pred,
                                                   const unsigned char* __restrict__ sdf,
                                                   float* __restrict__ out) {
    const int t   = blockIdx.x * 256 + threadIdx.x;   // 0..524287
    const int b   = t >> 16;
    const int hw4 = (t & 65535) << 2;
    const float*         pbase = pred + (size_t)b * C_ * HW_ + hw4;
    const unsigned char* sbase = sdf  + (size_t)b * C_ * HW_ + hw4;
    float4 den = {0.f, 0.f, 0.f, 0.f};
    float4 num = {0.f, 0.f, 0.f, 0.f};
    #pragma unroll
    for (int c = 0; c < C_; ++c) {
        const float4 v  = *(const float4*)(pbase + (size_t)c * HW_);
        const uchar4 sv = *(const uchar4*)(sbase + (size_t)c * HW_);
        const float e0 = __expf(v.x), e1 = __expf(v.y);
        const float e2 = __expf(v.z), e3 = __expf(v.w);
        den.x += e0; den.y += e1; den.z += e2; den.w += e3;
        num.x = fmaf(e0, (float)sv.x, num.x);
        num.y = fmaf(e1, (float)sv.y, num.y);
        num.z = fmaf(e2, (float)sv.z, num.z);
        num.w = fmaf(e3, (float)sv.w, num.w);
    }
    float acc = num.x / den.x + num.y / den.y + num.z / den.z + num.w / den.w;
    #pragma unroll
    for (int off = 32; off > 0; off >>= 1) acc += __shfl_down(acc, off);
    __shared__ float part[4];
    if ((threadIdx.x & 63) == 0) part[threadIdx.x >> 6] = acc;
    __syncthreads();
    if (threadIdx.x == 0) {
        float s = (part[0] + part[1]) + (part[2] + part[3]);
        atomicAdd(out, s * (1.0f / 39845888.0f));   // / (B*C*H*W)
    }
}

extern "C" void kernel_launch(void* const* d_in, const int* in_sizes, int n_in,
                              void* d_out, int out_size, void* d_ws, size_t ws_size,
                              hipStream_t stream) {
    const float* pred   = (const float*)d_in[0];
    const int*   target = (const int*)d_in[1];
    u64* masks = (u64*)d_ws;                               // 4,980,736 B
    unsigned char* sdf = (unsigned char*)d_ws + 4980736;   // 39,845,888 B
    float* out = (float*)d_out;

    hipMemsetAsync(out, 0, sizeof(float), stream);         // harness poisons d_out
    mask_kernel<<<512, 256, 0, stream>>>(target, masks);
    dilate_kernel<<<B_ * C_ * NSTRIP / 4, 256, 0, stream>>>(masks, sdf);
    loss_kernel<<<2048, 256, 0, stream>>>(pred, sdf, out);
}